// Round 1
// baseline (427.749 us; speedup 1.0000x reference)
//
#include <hip/hip_runtime.h>
#include <cstdint>
#include <cstddef>

typedef __bf16 bf16;
typedef bf16 bf16x8 __attribute__((ext_vector_type(8)));
typedef bf16 bf16x4 __attribute__((ext_vector_type(4)));
typedef float f32x4 __attribute__((ext_vector_type(4)));

typedef __attribute__((address_space(1))) void as1_void;
typedef __attribute__((address_space(3))) void as3_void;

#define INF __builtin_inff()

// ---------------------------------------------------------------------------
// cast fp32 -> bf16, 4 elems/thread
__global__ void z100_cast(const float* __restrict__ s, bf16* __restrict__ d, int n4) {
    int i = blockIdx.x * 256 + threadIdx.x;
    if (i >= n4) return;
    float4 v = ((const float4*)s)[i];
    bf16x4 o = { (bf16)v.x, (bf16)v.y, (bf16)v.z, (bf16)v.w };
    ((bf16x4*)d)[i] = o;
}

__global__ void z100_zero_bf16(bf16* __restrict__ p, int n) {
    int i = blockIdx.x * 256 + threadIdx.x;
    if (i < n) p[i] = (bf16)0.f;
}

// ---------------------------------------------------------------------------
// RMSNorm: one block per row; x fp32 [rows][ldx], out bf16 [rows][N]
__global__ __launch_bounds__(256) void z100_rmsnorm(
    const float* __restrict__ x, int ldx, const float* __restrict__ w,
    bf16* __restrict__ y, int N, float invN) {
    const int row = blockIdx.x;
    const float* xr = x + (size_t)row * ldx;
    float ss = 0.f;
    for (int i = threadIdx.x * 4; i < N; i += 1024) {
        float4 v = *(const float4*)(xr + i);
        ss += v.x * v.x + v.y * v.y + v.z * v.z + v.w * v.w;
    }
    #pragma unroll
    for (int d = 1; d < 64; d <<= 1) ss += __shfl_xor(ss, d);
    __shared__ float red[4];
    if ((threadIdx.x & 63) == 0) red[threadIdx.x >> 6] = ss;
    __syncthreads();
    float tot = red[0] + red[1] + red[2] + red[3];
    float rs = rsqrtf(tot * invN + 1e-6f);
    bf16* yr = y + (size_t)row * N;
    for (int i = threadIdx.x * 4; i < N; i += 1024) {
        float4 v = *(const float4*)(xr + i);
        float4 wv = *(const float4*)(w + i);
        bf16x4 o = { (bf16)(v.x * rs * wv.x), (bf16)(v.y * rs * wv.y),
                     (bf16)(v.z * rs * wv.z), (bf16)(v.w * rs * wv.w) };
        *(bf16x4*)(yr + i) = o;
    }
}

// ---------------------------------------------------------------------------
// GEMM: C[M][N] (fp32) = A[M][K] (bf16) @ B[N][K]^T (bf16)
// 128x128 tile, BK=32, 256 threads (4 waves, each 64x64)
__global__ __launch_bounds__(256) void z100_gemm_bt(
    const bf16* __restrict__ A, const bf16* __restrict__ B,
    float* __restrict__ C, int M, int N, int K) {
    __shared__ alignas(16) bf16 As[128 * 32];
    __shared__ alignas(16) bf16 Bs[128 * 32];
    const int tid = threadIdx.x;
    const int lane = tid & 63, wave = tid >> 6;
    const int l15 = lane & 15, l4 = lane >> 4;
    const int m0 = blockIdx.y * 128, n0 = blockIdx.x * 128;
    const int wr = (wave >> 1) * 64, wc = (wave & 1) * 64;

    f32x4 acc[4][4] = {};

    const int srow = lane >> 2;        // 0..15
    const int scol = (lane & 3) * 8;   // 0,8,16,24
    const size_t a_base = (size_t)(m0 + wave * 32 + srow) * K + scol;
    const size_t b_base = (size_t)(n0 + wave * 32 + srow) * K + scol;
    bf16* AsW = As + (wave * 32) * 32;
    bf16* BsW = Bs + (wave * 32) * 32;

    for (int k0 = 0; k0 < K; k0 += 32) {
        __syncthreads();
        __builtin_amdgcn_global_load_lds((as1_void*)(void*)(A + a_base + k0),
                                         (as3_void*)AsW, 16, 0, 0);
        __builtin_amdgcn_global_load_lds((as1_void*)(void*)(A + a_base + (size_t)16 * K + k0),
                                         (as3_void*)(AsW + 16 * 32), 16, 0, 0);
        __builtin_amdgcn_global_load_lds((as1_void*)(void*)(B + b_base + k0),
                                         (as3_void*)BsW, 16, 0, 0);
        __builtin_amdgcn_global_load_lds((as1_void*)(void*)(B + b_base + (size_t)16 * K + k0),
                                         (as3_void*)(BsW + 16 * 32), 16, 0, 0);
        __syncthreads();
        bf16x8 fa[4], fb[4];
        #pragma unroll
        for (int i = 0; i < 4; ++i)
            fa[i] = *(const bf16x8*)(As + (wr + 16 * i + l15) * 32 + 8 * l4);
        #pragma unroll
        for (int j = 0; j < 4; ++j)
            fb[j] = *(const bf16x8*)(Bs + (wc + 16 * j + l15) * 32 + 8 * l4);
        #pragma unroll
        for (int i = 0; i < 4; ++i)
            #pragma unroll
            for (int j = 0; j < 4; ++j)
                acc[i][j] = __builtin_amdgcn_mfma_f32_16x16x32_bf16(fa[i], fb[j], acc[i][j], 0, 0, 0);
    }

    #pragma unroll
    for (int i = 0; i < 4; ++i) {
        int row0 = m0 + wr + 16 * i + 4 * l4;
        #pragma unroll
        for (int j = 0; j < 4; ++j) {
            int col = n0 + wc + 16 * j + l15;
            if (col < N) {
                #pragma unroll
                for (int jj = 0; jj < 4; ++jj)
                    C[(size_t)(row0 + jj) * N + col] = acc[i][j][jj];
            }
        }
    }
}

// ---------------------------------------------------------------------------
// Q prep: q fp32 [S][3072] -> q_attn bf16 [H][S][192], rope on last 64, *scale
__global__ void z100_q_prep(const float* __restrict__ q,
                            const float* __restrict__ fc, const float* __restrict__ fs,
                            bf16* __restrict__ q_attn) {
    const int TOT = 2048 * 16 * 96;
    int u = blockIdx.x * 256 + threadIdx.x;
    if (u >= TOT) return;
    int e = u % 96;
    int sh = u / 96;
    int h = sh % 16, s = sh / 16;
    const float scale = 0.072168783649f;  // 1/sqrt(192)
    const float* qp = q + (size_t)s * 3072 + h * 192;
    bf16* o = q_attn + ((size_t)h * 2048 + s) * 192;
    if (e < 64) {
        o[2 * e]     = (bf16)(qp[2 * e] * scale);
        o[2 * e + 1] = (bf16)(qp[2 * e + 1] * scale);
    } else {
        int i = e - 64;
        float c = fc[s * 32 + i], sn = fs[s * 32 + i];
        float x1 = qp[128 + 2 * i], x2 = qp[128 + 2 * i + 1];
        o[128 + 2 * i]     = (bf16)((x1 * c - x2 * sn) * scale);
        o[128 + 2 * i + 1] = (bf16)((x1 * sn + x2 * c) * scale);
    }
}

// K prep: kvb fp32 [S][4096] (k_nope), kv fp32 [S][576] (k_pe src) -> k_attn [H][S][192]
__global__ void z100_k_prep(const float* __restrict__ kvb, const float* __restrict__ kv,
                            const float* __restrict__ fc, const float* __restrict__ fs,
                            bf16* __restrict__ k_attn) {
    const int TOT = 2048 * 16 * 96;
    int u = blockIdx.x * 256 + threadIdx.x;
    if (u >= TOT) return;
    int e = u % 96;
    int sh = u / 96;
    int h = sh % 16, s = sh / 16;
    bf16* o = k_attn + ((size_t)h * 2048 + s) * 192;
    if (e < 64) {
        const float* kp = kvb + (size_t)s * 4096 + h * 256;
        o[2 * e]     = (bf16)kp[2 * e];
        o[2 * e + 1] = (bf16)kp[2 * e + 1];
    } else {
        int i = e - 64;
        float c = fc[s * 32 + i], sn = fs[s * 32 + i];
        float x1 = kv[(size_t)s * 576 + 512 + 2 * i];
        float x2 = kv[(size_t)s * 576 + 512 + 2 * i + 1];
        o[128 + 2 * i]     = (bf16)(x1 * c - x2 * sn);
        o[128 + 2 * i + 1] = (bf16)(x1 * sn + x2 * c);
    }
}

// V transpose: kvb fp32 [S][4096] (v at h*256+128..) -> vt bf16 [H][128][S]
__global__ __launch_bounds__(256) void z100_v_trans(const float* __restrict__ kvb,
                                                    bf16* __restrict__ vt) {
    const int st = blockIdx.x, h = blockIdx.y;
    const int s0 = st * 64;
    __shared__ alignas(16) bf16 tile[64 * 132];
    const int tid = threadIdx.x;
    #pragma unroll
    for (int i = 0; i < 8; ++i) {
        int slot = i * 256 + tid;
        int r = slot >> 5, c4 = slot & 31;
        float4 v = *(const float4*)(kvb + (size_t)(s0 + r) * 4096 + h * 256 + 128 + c4 * 4);
        bf16x4 o = { (bf16)v.x, (bf16)v.y, (bf16)v.z, (bf16)v.w };
        *(bf16x4*)(tile + r * 132 + c4 * 4) = o;
    }
    __syncthreads();
    #pragma unroll
    for (int i = 0; i < 4; ++i) {
        int slot = i * 256 + tid;
        int d = slot >> 3, ch = slot & 7;
        bf16x8 o;
        #pragma unroll
        for (int j = 0; j < 8; ++j) o[j] = tile[(ch * 8 + j) * 132 + d];
        *(bf16x8*)(vt + ((size_t)h * 128 + d) * 2048 + s0 + ch * 8) = o;
    }
}

// ---------------------------------------------------------------------------
// Flash attention. grid (32 q-tiles, 16 heads), 256 threads (4 waves x 16 q rows)
__global__ __launch_bounds__(256) void z100_attn(
    const bf16* __restrict__ q_attn, const bf16* __restrict__ k_attn,
    const bf16* __restrict__ v_t, bf16* __restrict__ ao) {
    const int qt = blockIdx.x, h = blockIdx.y;
    const int q0 = qt * 64;
    const int tid = threadIdx.x;
    const int lane = tid & 63, wave = tid >> 6;
    const int l15 = lane & 15, l4 = lane >> 4;

    __shared__ alignas(16) bf16 Ks[64 * 192];
    __shared__ alignas(16) bf16 Vs[128 * 64];
    __shared__ alignas(16) bf16 Ps[4][16 * 64];

    const bf16* Qh = q_attn + (size_t)h * 2048 * 192;
    const bf16* Kh = k_attn + (size_t)h * 2048 * 192;
    const bf16* Vh = v_t + (size_t)h * 128 * 2048;

    bf16x8 qf[6];
    {
        const bf16* qr = Qh + (size_t)(q0 + wave * 16 + l15) * 192 + 8 * l4;
        #pragma unroll
        for (int c = 0; c < 6; ++c) qf[c] = *(const bf16x8*)(qr + 32 * c);
    }

    f32x4 oacc[8] = {};
    float m_r[4] = { -INF, -INF, -INF, -INF };
    float l_r[4] = { 0.f, 0.f, 0.f, 0.f };

    const int ntiles = qt + 1;
    for (int t = 0; t < ntiles; ++t) {
        const int k0 = t * 64;
        __syncthreads();
        // stage K tile [64][192] with XOR swizzle
        #pragma unroll
        for (int i = 0; i < 6; ++i) {
            int slot = i * 256 + tid;
            int r = slot / 24, ch = slot % 24;
            bf16x8 v = *(const bf16x8*)(Kh + (size_t)(k0 + r) * 192 + ch * 8);
            int byteo = (r * 384 + ch * 16) ^ ((r & 7) << 4);
            *(bf16x8*)((char*)Ks + byteo) = v;
        }
        // stage V^T tile [128][64] with XOR swizzle
        #pragma unroll
        for (int i = 0; i < 4; ++i) {
            int slot = i * 256 + tid;
            int d = slot >> 3, ch = slot & 7;
            bf16x8 v = *(const bf16x8*)(Vh + (size_t)d * 2048 + k0 + ch * 8);
            int byteo = (d * 128 + ch * 16) ^ ((d & 7) << 4);
            *(bf16x8*)((char*)Vs + byteo) = v;
        }
        __syncthreads();

        // scores: 4 n-tiles of 16 keys
        f32x4 sc[4];
        #pragma unroll
        for (int jt = 0; jt < 4; ++jt) {
            f32x4 a = { 0.f, 0.f, 0.f, 0.f };
            int r = 16 * jt + l15;
            #pragma unroll
            for (int c = 0; c < 6; ++c) {
                int byteo = (r * 384 + c * 64 + l4 * 16) ^ ((r & 7) << 4);
                bf16x8 kf = *(const bf16x8*)((char*)Ks + byteo);
                a = __builtin_amdgcn_mfma_f32_16x16x32_bf16(qf[c], kf, a, 0, 0, 0);
            }
            sc[jt] = a;
        }

        const int qbase = q0 + wave * 16 + 4 * l4;
        #pragma unroll
        for (int jj = 0; jj < 4; ++jj) {
            float mx = -INF;
            #pragma unroll
            for (int jt = 0; jt < 4; ++jt) {
                float s = sc[jt][jj];
                if (k0 + 16 * jt + l15 > qbase + jj) s = -INF;
                sc[jt][jj] = s;
                mx = fmaxf(mx, s);
            }
            mx = fmaxf(mx, __shfl_xor(mx, 1));
            mx = fmaxf(mx, __shfl_xor(mx, 2));
            mx = fmaxf(mx, __shfl_xor(mx, 4));
            mx = fmaxf(mx, __shfl_xor(mx, 8));
            float mnew = fmaxf(m_r[jj], mx);
            float corr = __expf(m_r[jj] - mnew);
            float rs = 0.f;
            #pragma unroll
            for (int jt = 0; jt < 4; ++jt) {
                float p = __expf(sc[jt][jj] - mnew);
                sc[jt][jj] = p;
                rs += p;
            }
            rs += __shfl_xor(rs, 1);
            rs += __shfl_xor(rs, 2);
            rs += __shfl_xor(rs, 4);
            rs += __shfl_xor(rs, 8);
            l_r[jj] = l_r[jj] * corr + rs;
            m_r[jj] = mnew;
            #pragma unroll
            for (int dt = 0; dt < 8; ++dt) oacc[dt][jj] *= corr;
        }

        // write P (D-layout) to LDS, swizzled
        #pragma unroll
        for (int jt = 0; jt < 4; ++jt) {
            #pragma unroll
            for (int jj = 0; jj < 4; ++jj) {
                int r = 4 * l4 + jj, c = 16 * jt + l15;
                int byteo = (r * 128 + c * 2) ^ ((r & 7) << 4);
                *(bf16*)((char*)Ps[wave] + byteo) = (bf16)sc[jt][jj];
            }
        }
        // P A-frags + PV
        bf16x8 pf[2];
        #pragma unroll
        for (int c2 = 0; c2 < 2; ++c2) {
            int byteo = (l15 * 128 + c2 * 64 + l4 * 16) ^ ((l15 & 7) << 4);
            pf[c2] = *(const bf16x8*)((char*)Ps[wave] + byteo);
        }
        #pragma unroll
        for (int dt = 0; dt < 8; ++dt) {
            #pragma unroll
            for (int c2 = 0; c2 < 2; ++c2) {
                int d = 16 * dt + l15;
                int byteo = (d * 128 + c2 * 64 + l4 * 16) ^ ((d & 7) << 4);
                bf16x8 vf = *(const bf16x8*)((char*)Vs + byteo);
                oacc[dt] = __builtin_amdgcn_mfma_f32_16x16x32_bf16(pf[c2], vf, oacc[dt], 0, 0, 0);
            }
        }
    }

    float inv_l[4];
    #pragma unroll
    for (int jj = 0; jj < 4; ++jj) inv_l[jj] = 1.f / l_r[jj];
    #pragma unroll
    for (int dt = 0; dt < 8; ++dt) {
        int d = 16 * dt + l15;
        #pragma unroll
        for (int jj = 0; jj < 4; ++jj) {
            int qg = q0 + wave * 16 + 4 * l4 + jj;
            ao[(size_t)qg * 2048 + h * 128 + d] = (bf16)(oacc[dt][jj] * inv_l[jj]);
        }
    }
}

// ---------------------------------------------------------------------------
extern "C" void kernel_launch(void* const* d_in, const int* in_sizes, int n_in,
                              void* d_out, int out_size, void* d_ws, size_t ws_size,
                              hipStream_t stream) {
    (void)in_sizes; (void)n_in; (void)out_size; (void)ws_size;
    const float* x     = (const float*)d_in[0];
    const float* fc    = (const float*)d_in[1];
    const float* fs    = (const float*)d_in[2];
    const float* wq_a  = (const float*)d_in[3];
    const float* q_ln  = (const float*)d_in[4];
    const float* wq_b  = (const float*)d_in[5];
    const float* wkv_a = (const float*)d_in[6];
    const float* kv_ln = (const float*)d_in[7];
    const float* wkv_b = (const float*)d_in[8];
    const float* wo    = (const float*)d_in[9];
    float* out = (float*)d_out;

    char* p = (char*)d_ws;
    auto alloc = [&](size_t bytes) {
        char* r = p;
        p += (bytes + 255) & ~(size_t)255;
        return r;
    };
    bf16* x_bf    = (bf16*)alloc(2048ull * 2048 * 2);
    bf16* wqa_bf  = (bf16*)alloc(1536ull * 2048 * 2);
    bf16* wqb_bf  = (bf16*)alloc(3072ull * 1536 * 2);
    bf16* wkva_bf = (bf16*)alloc(640ull * 2048 * 2);   // padded 576->640 rows
    bf16* wkvb_bf = (bf16*)alloc(4096ull * 512 * 2);
    bf16* wo_bf   = (bf16*)alloc(2048ull * 2048 * 2);
    float* qa_f   = (float*)alloc(2048ull * 1536 * 4);
    bf16* qan_bf  = (bf16*)alloc(2048ull * 1536 * 2);
    float* q_f    = (float*)alloc(2048ull * 3072 * 4);
    float* kv_f   = (float*)alloc(2048ull * 576 * 4);
    bf16* kvc_bf  = (bf16*)alloc(2048ull * 512 * 2);
    float* kvb_f  = (float*)alloc(2048ull * 4096 * 4);
    bf16* q_attn  = (bf16*)alloc(16ull * 2048 * 192 * 2);
    bf16* k_attn  = (bf16*)alloc(16ull * 2048 * 192 * 2);
    bf16* v_t     = (bf16*)alloc(16ull * 128 * 2048 * 2);
    bf16* ao_bf   = (bf16*)alloc(2048ull * 2048 * 2);

    // casts
    z100_cast<<<4096, 256, 0, stream>>>(x, x_bf, 1048576);
    z100_cast<<<3072, 256, 0, stream>>>(wq_a, wqa_bf, 786432);
    z100_cast<<<4608, 256, 0, stream>>>(wq_b, wqb_bf, 1179648);
    z100_cast<<<1152, 256, 0, stream>>>(wkv_a, wkva_bf, 294912);
    z100_zero_bf16<<<512, 256, 0, stream>>>(wkva_bf + 576ull * 2048, 131072);
    z100_cast<<<2048, 256, 0, stream>>>(wkv_b, wkvb_bf, 524288);
    z100_cast<<<4096, 256, 0, stream>>>(wo, wo_bf, 1048576);

    // q path
    z100_gemm_bt<<<dim3(12, 16), 256, 0, stream>>>(x_bf, wqa_bf, qa_f, 2048, 1536, 2048);
    z100_rmsnorm<<<2048, 256, 0, stream>>>(qa_f, 1536, q_ln, qan_bf, 1536, 1.f / 1536.f);
    z100_gemm_bt<<<dim3(24, 16), 256, 0, stream>>>(qan_bf, wqb_bf, q_f, 2048, 3072, 1536);

    // kv path
    z100_gemm_bt<<<dim3(5, 16), 256, 0, stream>>>(x_bf, wkva_bf, kv_f, 2048, 576, 2048);
    z100_rmsnorm<<<2048, 256, 0, stream>>>(kv_f, 576, kv_ln, kvc_bf, 512, 1.f / 512.f);
    z100_gemm_bt<<<dim3(32, 16), 256, 0, stream>>>(kvc_bf, wkvb_bf, kvb_f, 2048, 4096, 512);

    // attention prep
    z100_q_prep<<<12288, 256, 0, stream>>>(q_f, fc, fs, q_attn);
    z100_k_prep<<<12288, 256, 0, stream>>>(kvb_f, kv_f, fc, fs, k_attn);
    z100_v_trans<<<dim3(32, 16), 256, 0, stream>>>(kvb_f, v_t);

    // attention
    z100_attn<<<dim3(32, 16), 256, 0, stream>>>(q_attn, k_attn, v_t, ao_bf);

    // output projection (fp32 straight to d_out)
    z100_gemm_bt<<<dim3(16, 16), 256, 0, stream>>>(ao_bf, wo_bf, out, 2048, 2048, 2048);
}

// Round 2
// 348.176 us; speedup vs baseline: 1.2285x; 1.2285x over previous
//
#include <hip/hip_runtime.h>
#include <cstdint>
#include <cstddef>

typedef __bf16 bf16;
typedef bf16 bf16x8 __attribute__((ext_vector_type(8)));
typedef bf16 bf16x4 __attribute__((ext_vector_type(4)));
typedef float f32x4 __attribute__((ext_vector_type(4)));

typedef __attribute__((address_space(1))) void as1_void;
typedef __attribute__((address_space(3))) void as3_void;

#define INF __builtin_inff()

// ---------------------------------------------------------------------------
// cast fp32 -> bf16, 4 elems/thread
__global__ void z100_cast(const float* __restrict__ s, bf16* __restrict__ d, int n4) {
    int i = blockIdx.x * 256 + threadIdx.x;
    if (i >= n4) return;
    float4 v = ((const float4*)s)[i];
    bf16x4 o = { (bf16)v.x, (bf16)v.y, (bf16)v.z, (bf16)v.w };
    ((bf16x4*)d)[i] = o;
}

__global__ void z100_zero_bf16(bf16* __restrict__ p, int n) {
    int i = blockIdx.x * 256 + threadIdx.x;
    if (i < n) p[i] = (bf16)0.f;
}

// ---------------------------------------------------------------------------
// RMSNorm: one block per row; x fp32 [rows][ldx], out bf16 [rows][N]
__global__ __launch_bounds__(256) void z100_rmsnorm(
    const float* __restrict__ x, int ldx, const float* __restrict__ w,
    bf16* __restrict__ y, int N, float invN) {
    const int row = blockIdx.x;
    const float* xr = x + (size_t)row * ldx;
    float ss = 0.f;
    for (int i = threadIdx.x * 4; i < N; i += 1024) {
        float4 v = *(const float4*)(xr + i);
        ss += v.x * v.x + v.y * v.y + v.z * v.z + v.w * v.w;
    }
    #pragma unroll
    for (int d = 1; d < 64; d <<= 1) ss += __shfl_xor(ss, d);
    __shared__ float red[4];
    if ((threadIdx.x & 63) == 0) red[threadIdx.x >> 6] = ss;
    __syncthreads();
    float tot = red[0] + red[1] + red[2] + red[3];
    float rs = rsqrtf(tot * invN + 1e-6f);
    bf16* yr = y + (size_t)row * N;
    for (int i = threadIdx.x * 4; i < N; i += 1024) {
        float4 v = *(const float4*)(xr + i);
        float4 wv = *(const float4*)(w + i);
        bf16x4 o = { (bf16)(v.x * rs * wv.x), (bf16)(v.y * rs * wv.y),
                     (bf16)(v.z * rs * wv.z), (bf16)(v.w * rs * wv.w) };
        *(bf16x4*)(yr + i) = o;
    }
}

// ---------------------------------------------------------------------------
// GEMM: C[M][N] (fp32) = A[M][K] (bf16) @ B[N][K]^T (bf16)
// 128x128 tile, BK=32, 256 threads (4 waves, each 64x64)
__global__ __launch_bounds__(256) void z100_gemm_bt(
    const bf16* __restrict__ A, const bf16* __restrict__ B,
    float* __restrict__ C, int M, int N, int K) {
    __shared__ alignas(16) bf16 As[128 * 32];
    __shared__ alignas(16) bf16 Bs[128 * 32];
    const int tid = threadIdx.x;
    const int lane = tid & 63, wave = tid >> 6;
    const int l15 = lane & 15, l4 = lane >> 4;
    const int m0 = blockIdx.y * 128, n0 = blockIdx.x * 128;
    const int wr = (wave >> 1) * 64, wc = (wave & 1) * 64;

    f32x4 acc[4][4] = {};

    const int srow = lane >> 2;        // 0..15
    const int scol = (lane & 3) * 8;   // 0,8,16,24
    const size_t a_base = (size_t)(m0 + wave * 32 + srow) * K + scol;
    const size_t b_base = (size_t)(n0 + wave * 32 + srow) * K + scol;
    bf16* AsW = As + (wave * 32) * 32;
    bf16* BsW = Bs + (wave * 32) * 32;

    for (int k0 = 0; k0 < K; k0 += 32) {
        __syncthreads();
        __builtin_amdgcn_global_load_lds((as1_void*)(void*)(A + a_base + k0),
                                         (as3_void*)AsW, 16, 0, 0);
        __builtin_amdgcn_global_load_lds((as1_void*)(void*)(A + a_base + (size_t)16 * K + k0),
                                         (as3_void*)(AsW + 16 * 32), 16, 0, 0);
        __builtin_amdgcn_global_load_lds((as1_void*)(void*)(B + b_base + k0),
                                         (as3_void*)BsW, 16, 0, 0);
        __builtin_amdgcn_global_load_lds((as1_void*)(void*)(B + b_base + (size_t)16 * K + k0),
                                         (as3_void*)(BsW + 16 * 32), 16, 0, 0);
        __syncthreads();
        bf16x8 fa[4], fb[4];
        #pragma unroll
        for (int i = 0; i < 4; ++i)
            fa[i] = *(const bf16x8*)(As + (wr + 16 * i + l15) * 32 + 8 * l4);
        #pragma unroll
        for (int j = 0; j < 4; ++j)
            fb[j] = *(const bf16x8*)(Bs + (wc + 16 * j + l15) * 32 + 8 * l4);
        #pragma unroll
        for (int i = 0; i < 4; ++i)
            #pragma unroll
            for (int j = 0; j < 4; ++j)
                acc[i][j] = __builtin_amdgcn_mfma_f32_16x16x32_bf16(fa[i], fb[j], acc[i][j], 0, 0, 0);
    }

    #pragma unroll
    for (int i = 0; i < 4; ++i) {
        int row0 = m0 + wr + 16 * i + 4 * l4;
        #pragma unroll
        for (int j = 0; j < 4; ++j) {
            int col = n0 + wc + 16 * j + l15;
            if (col < N) {
                #pragma unroll
                for (int jj = 0; jj < 4; ++jj)
                    C[(size_t)(row0 + jj) * N + col] = acc[i][j][jj];
            }
        }
    }
}

// ---------------------------------------------------------------------------
// Q prep: q fp32 [S][3072] -> q_attn bf16 [H][S][192], rope on last 64, *scale
__global__ void z100_q_prep(const float* __restrict__ q,
                            const float* __restrict__ fc, const float* __restrict__ fs,
                            bf16* __restrict__ q_attn) {
    const int TOT = 2048 * 16 * 96;
    int u = blockIdx.x * 256 + threadIdx.x;
    if (u >= TOT) return;
    int e = u % 96;
    int sh = u / 96;
    int h = sh % 16, s = sh / 16;
    const float scale = 0.072168783649f;  // 1/sqrt(192)
    const float* qp = q + (size_t)s * 3072 + h * 192;
    bf16* o = q_attn + ((size_t)h * 2048 + s) * 192;
    if (e < 64) {
        o[2 * e]     = (bf16)(qp[2 * e] * scale);
        o[2 * e + 1] = (bf16)(qp[2 * e + 1] * scale);
    } else {
        int i = e - 64;
        float c = fc[s * 32 + i], sn = fs[s * 32 + i];
        float x1 = qp[128 + 2 * i], x2 = qp[128 + 2 * i + 1];
        o[128 + 2 * i]     = (bf16)((x1 * c - x2 * sn) * scale);
        o[128 + 2 * i + 1] = (bf16)((x1 * sn + x2 * c) * scale);
    }
}

// K prep: kvb fp32 [S][4096] (k_nope), kv fp32 [S][576] (k_pe src) -> k_attn [H][S][192]
__global__ void z100_k_prep(const float* __restrict__ kvb, const float* __restrict__ kv,
                            const float* __restrict__ fc, const float* __restrict__ fs,
                            bf16* __restrict__ k_attn) {
    const int TOT = 2048 * 16 * 96;
    int u = blockIdx.x * 256 + threadIdx.x;
    if (u >= TOT) return;
    int e = u % 96;
    int sh = u / 96;
    int h = sh % 16, s = sh / 16;
    bf16* o = k_attn + ((size_t)h * 2048 + s) * 192;
    if (e < 64) {
        const float* kp = kvb + (size_t)s * 4096 + h * 256;
        o[2 * e]     = (bf16)kp[2 * e];
        o[2 * e + 1] = (bf16)kp[2 * e + 1];
    } else {
        int i = e - 64;
        float c = fc[s * 32 + i], sn = fs[s * 32 + i];
        float x1 = kv[(size_t)s * 576 + 512 + 2 * i];
        float x2 = kv[(size_t)s * 576 + 512 + 2 * i + 1];
        o[128 + 2 * i]     = (bf16)(x1 * c - x2 * sn);
        o[128 + 2 * i + 1] = (bf16)(x1 * sn + x2 * c);
    }
}

// V transpose: kvb fp32 [S][4096] (v at h*256+128..) -> vt bf16 [H][128][S]
__global__ __launch_bounds__(256) void z100_v_trans(const float* __restrict__ kvb,
                                                    bf16* __restrict__ vt) {
    const int st = blockIdx.x, h = blockIdx.y;
    const int s0 = st * 64;
    __shared__ alignas(16) bf16 tile[64 * 132];
    const int tid = threadIdx.x;
    #pragma unroll
    for (int i = 0; i < 8; ++i) {
        int slot = i * 256 + tid;
        int r = slot >> 5, c4 = slot & 31;
        float4 v = *(const float4*)(kvb + (size_t)(s0 + r) * 4096 + h * 256 + 128 + c4 * 4);
        bf16x4 o = { (bf16)v.x, (bf16)v.y, (bf16)v.z, (bf16)v.w };
        *(bf16x4*)(tile + r * 132 + c4 * 4) = o;
    }
    __syncthreads();
    #pragma unroll
    for (int i = 0; i < 4; ++i) {
        int slot = i * 256 + tid;
        int d = slot >> 3, ch = slot & 7;
        bf16x8 o;
        #pragma unroll
        for (int j = 0; j < 8; ++j) o[j] = tile[(ch * 8 + j) * 132 + d];
        *(bf16x8*)(vt + ((size_t)h * 128 + d) * 2048 + s0 + ch * 8) = o;
    }
}

// ---------------------------------------------------------------------------
// Flash attention, split-K, swapped QK^T (scores transposed -> lane-local rows).
// grid (32 q-tiles, 16 heads, 2 chunks), 256 threads (4 waves x 16 q rows).
// Each block: q rows [qt*64, qt*64+64), keys [ch*1024, min(qt*64+64, ch*1024+1024)).
// Writes UNNORMALIZED partial O (bf16) + m,l (f32); combine kernel merges.
__global__ __launch_bounds__(256) void z100_attn(
    const bf16* __restrict__ q_attn, const bf16* __restrict__ k_attn,
    const bf16* __restrict__ v_t, bf16* __restrict__ opart, float* __restrict__ ml) {
    const int qt = blockIdx.x, h = blockIdx.y, chk = blockIdx.z;
    const int q0 = qt * 64;
    const int kstart = chk * 1024;
    const int kend = min(q0 + 64, kstart + 1024);
    if (kstart >= kend) return;

    const int tid = threadIdx.x;
    const int lane = tid & 63, wave = tid >> 6;
    const int l15 = lane & 15, l4 = lane >> 4;

    __shared__ alignas(16) bf16 Ks[64 * 192];
    __shared__ alignas(16) bf16 Vs[128 * 64];

    const bf16* Qh = q_attn + (size_t)h * 2048 * 192;
    const bf16* Kh = k_attn + (size_t)h * 2048 * 192;
    const bf16* Vh = v_t + (size_t)h * 128 * 2048;

    bf16x8 qf[6];
    {
        const bf16* qr = Qh + (size_t)(q0 + wave * 16 + l15) * 192 + 8 * l4;
        #pragma unroll
        for (int c = 0; c < 6; ++c) qf[c] = *(const bf16x8*)(qr + 32 * c);
    }

    f32x4 oacc[8] = {};
    float m_r = -INF, l_r = 0.f;

    for (int k0 = kstart; k0 < kend; k0 += 64) {
        __syncthreads();
        // stage K tile: LDS row r holds key k0+perm(r); perm chosen so that the
        // transposed-score D-layout coincides with PV's A-fragment layout.
        // r bits [kt1 kt0 g1 g0 r1 r0] -> k bits [kt1][g1 g0][kt0][r1 r0]
        #pragma unroll
        for (int i = 0; i < 6; ++i) {
            int slot = i * 256 + tid;
            int r = slot / 24, chn = slot % 24;
            int ksrc = (r & 0x23) | ((r & 0x0C) << 1) | ((r & 0x10) >> 2);
            bf16x8 v = *(const bf16x8*)(Kh + (size_t)(k0 + ksrc) * 192 + chn * 8);
            int byteo = (r * 384 + chn * 16) ^ ((r & 7) << 4);
            *(bf16x8*)((char*)Ks + byteo) = v;
        }
        // stage V^T tile [128][64] with XOR swizzle
        #pragma unroll
        for (int i = 0; i < 4; ++i) {
            int slot = i * 256 + tid;
            int d = slot >> 3, chn = slot & 7;
            bf16x8 v = *(const bf16x8*)(Vh + (size_t)d * 2048 + k0 + chn * 8);
            int byteo = (d * 128 + chn * 16) ^ ((d & 7) << 4);
            *(bf16x8*)((char*)Vs + byteo) = v;
        }
        __syncthreads();

        // QK^T swapped: mfma(K, Q) -> D[key][q]; lane holds 16 scores for q = l15.
        f32x4 sc[4];
        #pragma unroll
        for (int kt = 0; kt < 4; ++kt) {
            f32x4 a = { 0.f, 0.f, 0.f, 0.f };
            int r = 16 * kt + l15;
            #pragma unroll
            for (int c = 0; c < 6; ++c) {
                int byteo = (r * 384 + c * 64 + l4 * 16) ^ ((r & 7) << 4);
                bf16x8 kf = *(const bf16x8*)((char*)Ks + byteo);
                a = __builtin_amdgcn_mfma_f32_16x16x32_bf16(kf, qf[c], a, 0, 0, 0);
            }
            sc[kt] = a;
        }

        // causal mask: only the diagonal tile needs it
        if (k0 == q0) {
            int qrow = wave * 16 + l15;
            #pragma unroll
            for (int kt = 0; kt < 4; ++kt)
                #pragma unroll
                for (int r = 0; r < 4; ++r) {
                    int kl = ((kt >> 1) << 5) | (l4 << 3) | ((kt & 1) << 2) | r;
                    if (kl > qrow) sc[kt][r] = -INF;
                }
        }

        // online softmax: row = this lane's q; reduce over l4 groups (2 shuffles)
        float mx = -INF;
        #pragma unroll
        for (int kt = 0; kt < 4; ++kt)
            #pragma unroll
            for (int r = 0; r < 4; ++r) mx = fmaxf(mx, sc[kt][r]);
        mx = fmaxf(mx, __shfl_xor(mx, 16));
        mx = fmaxf(mx, __shfl_xor(mx, 32));
        float mnew = fmaxf(m_r, mx);
        float corr = __expf(m_r - mnew);
        float rs = 0.f;
        #pragma unroll
        for (int kt = 0; kt < 4; ++kt)
            #pragma unroll
            for (int r = 0; r < 4; ++r) {
                float pv = __expf(sc[kt][r] - mnew);
                sc[kt][r] = pv;
                rs += pv;
            }
        rs += __shfl_xor(rs, 16);
        rs += __shfl_xor(rs, 32);
        l_r = l_r * corr + rs;
        m_r = mnew;

        // rescale oacc: oacc rows are q = 4*l4+reg -> fetch corr from lane l15=4*l4+reg
        float c_r[4];
        #pragma unroll
        for (int r = 0; r < 4; ++r) c_r[r] = __shfl(corr, 20 * l4 + r);
        #pragma unroll
        for (int dt = 0; dt < 8; ++dt)
            #pragma unroll
            for (int r = 0; r < 4; ++r) oacc[dt][r] *= c_r[r];

        // P -> A-fragments: pure in-lane relabeling thanks to the K staging perm
        bf16x8 pf[2];
        #pragma unroll
        for (int c2 = 0; c2 < 2; ++c2)
            #pragma unroll
            for (int i = 0; i < 8; ++i)
                pf[c2][i] = (bf16)sc[2 * c2 + (i >> 2)][i & 3];

        #pragma unroll
        for (int dt = 0; dt < 8; ++dt) {
            #pragma unroll
            for (int c2 = 0; c2 < 2; ++c2) {
                int d = 16 * dt + l15;
                int byteo = (d * 128 + c2 * 64 + l4 * 16) ^ ((d & 7) << 4);
                bf16x8 vf = *(const bf16x8*)((char*)Vs + byteo);
                oacc[dt] = __builtin_amdgcn_mfma_f32_16x16x32_bf16(pf[c2], vf, oacc[dt], 0, 0, 0);
            }
        }
    }

    // write partial: slot = ((h*32+qt)*2 + chk)
    const int slot = (h * 32 + qt) * 2 + chk;
    if (lane < 16) {
        ml[(size_t)slot * 128 + wave * 16 + lane] = m_r;
        ml[(size_t)slot * 128 + 64 + wave * 16 + lane] = l_r;
    }
    bf16* ob = opart + (size_t)slot * 8192;
    #pragma unroll
    for (int dt = 0; dt < 8; ++dt) {
        int d = 16 * dt + l15;
        #pragma unroll
        for (int r = 0; r < 4; ++r) {
            int qr = wave * 16 + 4 * l4 + r;
            ob[qr * 128 + d] = (bf16)oacc[dt][r];
        }
    }
}

// combine partials -> ao bf16 [S][H*128]
__global__ __launch_bounds__(256) void z100_attn_combine(
    const bf16* __restrict__ opart, const float* __restrict__ ml, bf16* __restrict__ ao) {
    const int qt = blockIdx.x, h = blockIdx.y;
    const int t = threadIdx.x;
    const int qr = t >> 2, d0 = (t & 3) * 32;
    const int slot = (h * 32 + qt) * 2;
    float m0 = ml[(size_t)slot * 128 + qr], l0 = ml[(size_t)slot * 128 + 64 + qr];
    float w0 = 1.f, w1 = 0.f, L = l0;
    const bool two = (qt >= 16);
    if (two) {
        float m1 = ml[(size_t)(slot + 1) * 128 + qr];
        float l1 = ml[(size_t)(slot + 1) * 128 + 64 + qr];
        float M = fmaxf(m0, m1);
        w0 = __expf(m0 - M);
        w1 = __expf(m1 - M);
        L = w0 * l0 + w1 * l1;
    }
    float invL = 1.f / L;
    const bf16* p0 = opart + (size_t)slot * 8192 + qr * 128 + d0;
    const bf16* p1 = p0 + 8192;
    bf16* orow = ao + (size_t)(qt * 64 + qr) * 2048 + h * 128 + d0;
    for (int d = 0; d < 32; d += 8) {
        bf16x8 a = *(const bf16x8*)(p0 + d);
        bf16x8 o;
        if (two) {
            bf16x8 b = *(const bf16x8*)(p1 + d);
            #pragma unroll
            for (int i = 0; i < 8; ++i)
                o[i] = (bf16)((w0 * (float)a[i] + w1 * (float)b[i]) * invL);
        } else {
            #pragma unroll
            for (int i = 0; i < 8; ++i)
                o[i] = (bf16)((float)a[i] * invL);
        }
        *(bf16x8*)(orow + d) = o;
    }
}

// ---------------------------------------------------------------------------
extern "C" void kernel_launch(void* const* d_in, const int* in_sizes, int n_in,
                              void* d_out, int out_size, void* d_ws, size_t ws_size,
                              hipStream_t stream) {
    (void)in_sizes; (void)n_in; (void)out_size; (void)ws_size;
    const float* x     = (const float*)d_in[0];
    const float* fc    = (const float*)d_in[1];
    const float* fs    = (const float*)d_in[2];
    const float* wq_a  = (const float*)d_in[3];
    const float* q_ln  = (const float*)d_in[4];
    const float* wq_b  = (const float*)d_in[5];
    const float* wkv_a = (const float*)d_in[6];
    const float* kv_ln = (const float*)d_in[7];
    const float* wkv_b = (const float*)d_in[8];
    const float* wo    = (const float*)d_in[9];
    float* out = (float*)d_out;

    char* p = (char*)d_ws;
    auto alloc = [&](size_t bytes) {
        char* r = p;
        p += (bytes + 255) & ~(size_t)255;
        return r;
    };
    bf16* x_bf    = (bf16*)alloc(2048ull * 2048 * 2);
    bf16* wqa_bf  = (bf16*)alloc(1536ull * 2048 * 2);
    bf16* wqb_bf  = (bf16*)alloc(3072ull * 1536 * 2);
    bf16* wkva_bf = (bf16*)alloc(640ull * 2048 * 2);   // padded 576->640 rows
    bf16* wkvb_bf = (bf16*)alloc(4096ull * 512 * 2);
    bf16* wo_bf   = (bf16*)alloc(2048ull * 2048 * 2);
    float* qa_f   = (float*)alloc(2048ull * 1536 * 4);
    bf16* qan_bf  = (bf16*)alloc(2048ull * 1536 * 2);
    float* q_f    = (float*)alloc(2048ull * 3072 * 4);
    float* kv_f   = (float*)alloc(2048ull * 576 * 4);
    bf16* kvc_bf  = (bf16*)alloc(2048ull * 512 * 2);
    float* kvb_f  = (float*)alloc(2048ull * 4096 * 4);
    bf16* q_attn  = (bf16*)alloc(16ull * 2048 * 192 * 2);
    bf16* k_attn  = (bf16*)alloc(16ull * 2048 * 192 * 2);
    bf16* v_t     = (bf16*)alloc(16ull * 128 * 2048 * 2);
    bf16* ao_bf   = (bf16*)alloc(2048ull * 2048 * 2);
    bf16* opart   = (bf16*)alloc(1024ull * 8192 * 2);   // [16*32*2 slots][64*128]
    float* mlbuf  = (float*)alloc(1024ull * 128 * 4);   // [slots][2][64]

    // casts
    z100_cast<<<4096, 256, 0, stream>>>(x, x_bf, 1048576);
    z100_cast<<<3072, 256, 0, stream>>>(wq_a, wqa_bf, 786432);
    z100_cast<<<4608, 256, 0, stream>>>(wq_b, wqb_bf, 1179648);
    z100_cast<<<1152, 256, 0, stream>>>(wkv_a, wkva_bf, 294912);
    z100_zero_bf16<<<512, 256, 0, stream>>>(wkva_bf + 576ull * 2048, 131072);
    z100_cast<<<2048, 256, 0, stream>>>(wkv_b, wkvb_bf, 524288);
    z100_cast<<<4096, 256, 0, stream>>>(wo, wo_bf, 1048576);

    // q path
    z100_gemm_bt<<<dim3(12, 16), 256, 0, stream>>>(x_bf, wqa_bf, qa_f, 2048, 1536, 2048);
    z100_rmsnorm<<<2048, 256, 0, stream>>>(qa_f, 1536, q_ln, qan_bf, 1536, 1.f / 1536.f);
    z100_gemm_bt<<<dim3(24, 16), 256, 0, stream>>>(qan_bf, wqb_bf, q_f, 2048, 3072, 1536);

    // kv path
    z100_gemm_bt<<<dim3(5, 16), 256, 0, stream>>>(x_bf, wkva_bf, kv_f, 2048, 576, 2048);
    z100_rmsnorm<<<2048, 256, 0, stream>>>(kv_f, 576, kv_ln, kvc_bf, 512, 1.f / 512.f);
    z100_gemm_bt<<<dim3(32, 16), 256, 0, stream>>>(kvc_bf, wkvb_bf, kvb_f, 2048, 4096, 512);

    // attention prep
    z100_q_prep<<<12288, 256, 0, stream>>>(q_f, fc, fs, q_attn);
    z100_k_prep<<<12288, 256, 0, stream>>>(kvb_f, kv_f, fc, fs, k_attn);
    z100_v_trans<<<dim3(32, 16), 256, 0, stream>>>(kvb_f, v_t);

    // attention (split-K) + combine
    z100_attn<<<dim3(32, 16, 2), 256, 0, stream>>>(q_attn, k_attn, v_t, opart, mlbuf);
    z100_attn_combine<<<dim3(32, 16), 256, 0, stream>>>(opart, mlbuf, ao_bf);

    // output projection (fp32 straight to d_out)
    z100_gemm_bt<<<dim3(16, 16), 256, 0, stream>>>(ao_bf, wo_bf, out, 2048, 2048, 2048);
}

// Round 3
// 290.258 us; speedup vs baseline: 1.4737x; 1.1995x over previous
//
#include <hip/hip_runtime.h>
#include <cstdint>
#include <cstddef>

typedef __bf16 bf16;
typedef bf16 bf16x8 __attribute__((ext_vector_type(8)));
typedef bf16 bf16x4 __attribute__((ext_vector_type(4)));
typedef float f32x4 __attribute__((ext_vector_type(4)));

typedef __attribute__((address_space(1))) void as1_void;
typedef __attribute__((address_space(3))) void as3_void;

#define INF __builtin_inff()

// ---------------------------------------------------------------------------
// cast fp32 -> bf16, 4 elems/thread
__global__ void z100_cast(const float* __restrict__ s, bf16* __restrict__ d, int n4) {
    int i = blockIdx.x * 256 + threadIdx.x;
    if (i >= n4) return;
    float4 v = ((const float4*)s)[i];
    bf16x4 o = { (bf16)v.x, (bf16)v.y, (bf16)v.z, (bf16)v.w };
    ((bf16x4*)d)[i] = o;
}

__global__ void z100_zero_bf16(bf16* __restrict__ p, int n) {
    int i = blockIdx.x * 256 + threadIdx.x;
    if (i < n) p[i] = (bf16)0.f;
}

// ---------------------------------------------------------------------------
// RMSNorm: one block per row; x fp32 [rows][ldx], out bf16 [rows][N]
__global__ __launch_bounds__(256) void z100_rmsnorm(
    const float* __restrict__ x, int ldx, const float* __restrict__ w,
    bf16* __restrict__ y, int N, float invN) {
    const int row = blockIdx.x;
    const float* xr = x + (size_t)row * ldx;
    float ss = 0.f;
    for (int i = threadIdx.x * 4; i < N; i += 1024) {
        float4 v = *(const float4*)(xr + i);
        ss += v.x * v.x + v.y * v.y + v.z * v.z + v.w * v.w;
    }
    #pragma unroll
    for (int d = 1; d < 64; d <<= 1) ss += __shfl_xor(ss, d);
    __shared__ float red[4];
    if ((threadIdx.x & 63) == 0) red[threadIdx.x >> 6] = ss;
    __syncthreads();
    float tot = red[0] + red[1] + red[2] + red[3];
    float rs = rsqrtf(tot * invN + 1e-6f);
    bf16* yr = y + (size_t)row * N;
    for (int i = threadIdx.x * 4; i < N; i += 1024) {
        float4 v = *(const float4*)(xr + i);
        float4 wv = *(const float4*)(w + i);
        bf16x4 o = { (bf16)(v.x * rs * wv.x), (bf16)(v.y * rs * wv.y),
                     (bf16)(v.z * rs * wv.z), (bf16)(v.w * rs * wv.w) };
        *(bf16x4*)(yr + i) = o;
    }
}

// ---------------------------------------------------------------------------
// GEMM: C[M][N] (fp32, ldc) = A[M][K] (bf16) @ B[N][K]^T (bf16)
// 128x128 tile, BK=32, 256 threads, 2-phase double-buffered async staging.
__global__ __launch_bounds__(256) void z100_gemm_bt(
    const bf16* __restrict__ A, const bf16* __restrict__ B,
    float* __restrict__ C, int M, int N, int K, int ldc) {
    __shared__ alignas(16) bf16 As[2][128 * 32];
    __shared__ alignas(16) bf16 Bs[2][128 * 32];
    const int tid = threadIdx.x;
    const int lane = tid & 63, wave = tid >> 6;
    const int l15 = lane & 15, l4 = lane >> 4;
    const int m0 = blockIdx.y * 128, n0 = blockIdx.x * 128;
    const int wr = (wave >> 1) * 64, wc = (wave & 1) * 64;

    f32x4 acc[4][4] = {};

    const int srow = lane >> 2;        // 0..15
    const int scol = (lane & 3) * 8;   // 0,8,16,24
    const size_t a_base = (size_t)(m0 + wave * 32 + srow) * K + scol;
    const size_t b_base = (size_t)(n0 + wave * 32 + srow) * K + scol;

    auto stage = [&](int buf, int k0) {
        bf16* AsW = &As[buf][0] + wave * 32 * 32;
        bf16* BsW = &Bs[buf][0] + wave * 32 * 32;
        __builtin_amdgcn_global_load_lds((as1_void*)(void*)(A + a_base + k0),
                                         (as3_void*)AsW, 16, 0, 0);
        __builtin_amdgcn_global_load_lds((as1_void*)(void*)(A + a_base + (size_t)16 * K + k0),
                                         (as3_void*)(AsW + 512), 16, 0, 0);
        __builtin_amdgcn_global_load_lds((as1_void*)(void*)(B + b_base + k0),
                                         (as3_void*)BsW, 16, 0, 0);
        __builtin_amdgcn_global_load_lds((as1_void*)(void*)(B + b_base + (size_t)16 * K + k0),
                                         (as3_void*)(BsW + 512), 16, 0, 0);
    };

    stage(0, 0);
    __syncthreads();
    int buf = 0;
    for (int k0 = 0; k0 < K; k0 += 32) {
        if (k0 + 32 < K) stage(buf ^ 1, k0 + 32);   // prefetch overlaps compute
        bf16x8 fa[4], fb[4];
        #pragma unroll
        for (int i = 0; i < 4; ++i)
            fa[i] = *(const bf16x8*)(&As[buf][0] + (wr + 16 * i + l15) * 32 + 8 * l4);
        #pragma unroll
        for (int j = 0; j < 4; ++j)
            fb[j] = *(const bf16x8*)(&Bs[buf][0] + (wc + 16 * j + l15) * 32 + 8 * l4);
        #pragma unroll
        for (int i = 0; i < 4; ++i)
            #pragma unroll
            for (int j = 0; j < 4; ++j)
                acc[i][j] = __builtin_amdgcn_mfma_f32_16x16x32_bf16(fa[i], fb[j], acc[i][j], 0, 0, 0);
        __syncthreads();   // drains prefetch vmcnt + syncs buffer swap
        buf ^= 1;
    }

    #pragma unroll
    for (int i = 0; i < 4; ++i) {
        int row0 = m0 + wr + 16 * i + 4 * l4;
        #pragma unroll
        for (int j = 0; j < 4; ++j) {
            int col = n0 + wc + 16 * j + l15;
            if (col < N) {
                #pragma unroll
                for (int jj = 0; jj < 4; ++jj)
                    C[(size_t)(row0 + jj) * ldc + col] = acc[i][j][jj];
            }
        }
    }
}

// ---------------------------------------------------------------------------
// Q prep: q fp32 [S][3072] -> q_attn bf16 [H][S][192], rope on last 64, *scale
__global__ void z100_q_prep(const float* __restrict__ q,
                            const float* __restrict__ fc, const float* __restrict__ fs,
                            bf16* __restrict__ q_attn) {
    const int TOT = 2048 * 16 * 96;
    int u = blockIdx.x * 256 + threadIdx.x;
    if (u >= TOT) return;
    int e = u % 96;
    int sh = u / 96;
    int h = sh % 16, s = sh / 16;
    const float scale = 0.072168783649f;  // 1/sqrt(192)
    const float* qp = q + (size_t)s * 3072 + h * 192;
    bf16* o = q_attn + ((size_t)h * 2048 + s) * 192;
    if (e < 64) {
        o[2 * e]     = (bf16)(qp[2 * e] * scale);
        o[2 * e + 1] = (bf16)(qp[2 * e + 1] * scale);
    } else {
        int i = e - 64;
        float c = fc[s * 32 + i], sn = fs[s * 32 + i];
        float x1 = qp[128 + 2 * i], x2 = qp[128 + 2 * i + 1];
        o[128 + 2 * i]     = (bf16)((x1 * c - x2 * sn) * scale);
        o[128 + 2 * i + 1] = (bf16)((x1 * sn + x2 * c) * scale);
    }
}

// K prep: kvb fp32 [S][4096] (k_nope), kpe fp32 [S][kpe_ld] -> k_attn [H][S][192]
__global__ void z100_k_prep(const float* __restrict__ kvb, const float* __restrict__ kpe,
                            int kpe_ld,
                            const float* __restrict__ fc, const float* __restrict__ fs,
                            bf16* __restrict__ k_attn) {
    const int TOT = 2048 * 16 * 96;
    int u = blockIdx.x * 256 + threadIdx.x;
    if (u >= TOT) return;
    int e = u % 96;
    int sh = u / 96;
    int h = sh % 16, s = sh / 16;
    bf16* o = k_attn + ((size_t)h * 2048 + s) * 192;
    if (e < 64) {
        const float* kp = kvb + (size_t)s * 4096 + h * 256;
        o[2 * e]     = (bf16)kp[2 * e];
        o[2 * e + 1] = (bf16)kp[2 * e + 1];
    } else {
        int i = e - 64;
        float c = fc[s * 32 + i], sn = fs[s * 32 + i];
        float x1 = kpe[(size_t)s * kpe_ld + 2 * i];
        float x2 = kpe[(size_t)s * kpe_ld + 2 * i + 1];
        o[128 + 2 * i]     = (bf16)(x1 * c - x2 * sn);
        o[128 + 2 * i + 1] = (bf16)(x1 * sn + x2 * c);
    }
}

// V transpose: kvb fp32 [S][4096] (v at h*256+128..) -> vt bf16 [H][128][S]
__global__ __launch_bounds__(256) void z100_v_trans(const float* __restrict__ kvb,
                                                    bf16* __restrict__ vt) {
    const int st = blockIdx.x, h = blockIdx.y;
    const int s0 = st * 64;
    __shared__ alignas(16) bf16 tile[64 * 132];
    const int tid = threadIdx.x;
    #pragma unroll
    for (int i = 0; i < 8; ++i) {
        int slot = i * 256 + tid;
        int r = slot >> 5, c4 = slot & 31;
        float4 v = *(const float4*)(kvb + (size_t)(s0 + r) * 4096 + h * 256 + 128 + c4 * 4);
        bf16x4 o = { (bf16)v.x, (bf16)v.y, (bf16)v.z, (bf16)v.w };
        *(bf16x4*)(tile + r * 132 + c4 * 4) = o;
    }
    __syncthreads();
    #pragma unroll
    for (int i = 0; i < 4; ++i) {
        int slot = i * 256 + tid;
        int d = slot >> 3, ch = slot & 7;
        bf16x8 o;
        #pragma unroll
        for (int j = 0; j < 8; ++j) o[j] = tile[(ch * 8 + j) * 132 + d];
        *(bf16x8*)(vt + ((size_t)h * 128 + d) * 2048 + s0 + ch * 8) = o;
    }
}

// ---------------------------------------------------------------------------
// Flash attention, split-K(4x512), swapped QK^T, double-buffered async staging.
// grid (32 q-tiles, 16 heads, 4 chunks), 256 threads (4 waves x 16 q rows).
__global__ __launch_bounds__(256) void z100_attn(
    const bf16* __restrict__ q_attn, const bf16* __restrict__ k_attn,
    const bf16* __restrict__ v_t, bf16* __restrict__ opart, float* __restrict__ ml) {
    const int qt = blockIdx.x, h = blockIdx.y, chk = blockIdx.z;
    const int q0 = qt * 64;
    const int kstart = chk * 512;
    const int kend = min(q0 + 64, kstart + 512);
    if (kstart >= kend) return;

    const int tid = threadIdx.x;
    const int lane = tid & 63, wave = tid >> 6;
    const int l15 = lane & 15, l4 = lane >> 4;

    __shared__ alignas(16) bf16 Ks[2][64 * 192];
    __shared__ alignas(16) bf16 Vs[2][128 * 64];

    const bf16* Qh = q_attn + (size_t)h * 2048 * 192;
    const bf16* Kh = k_attn + (size_t)h * 2048 * 192;
    const bf16* Vh = v_t + (size_t)h * 128 * 2048;

    bf16x8 qf[6];
    {
        const bf16* qr = Qh + (size_t)(q0 + wave * 16 + l15) * 192 + 8 * l4;
        #pragma unroll
        for (int c = 0; c < 6; ++c) qf[c] = *(const bf16x8*)(qr + 32 * c);
    }

    // Precompute per-lane staging source offsets.
    // LDS dest is LINEAR (global_load_lds: base + lane*16); the K-row
    // permutation and XOR bank swizzle are applied to the GLOBAL source so the
    // read side (swizzled ds_read) sees the same layout as before.
    int koff[6], voff[4];
    #pragma unroll
    for (int i = 0; i < 6; ++i) {
        int off = (wave * 6 + i) * 1024 + lane * 16;   // byte offset in K tile
        int r = off / 384;
        int ch = (off % 384) >> 4;
        int ksrc = (r & 0x23) | ((r & 0x0C) << 1) | ((r & 0x10) >> 2);
        koff[i] = ksrc * 192 + (ch ^ (r & 7)) * 8;
    }
    #pragma unroll
    for (int i = 0; i < 4; ++i) {
        int off = (wave * 4 + i) * 1024 + lane * 16;   // byte offset in V tile
        int d = off >> 7;
        int ch = (off >> 4) & 7;
        voff[i] = d * 2048 + (ch ^ (d & 7)) * 8;
    }

    auto stage = [&](int buf, int k0) {
        #pragma unroll
        for (int i = 0; i < 6; ++i)
            __builtin_amdgcn_global_load_lds(
                (as1_void*)(void*)(Kh + (size_t)k0 * 192 + koff[i]),
                (as3_void*)((char*)&Ks[buf][0] + (wave * 6 + i) * 1024), 16, 0, 0);
        #pragma unroll
        for (int i = 0; i < 4; ++i)
            __builtin_amdgcn_global_load_lds(
                (as1_void*)(void*)(Vh + k0 + voff[i]),
                (as3_void*)((char*)&Vs[buf][0] + (wave * 4 + i) * 1024), 16, 0, 0);
    };

    f32x4 oacc[8] = {};
    float m_r = -INF, l_r = 0.f;
    const int nt = (kend - kstart) >> 6;

    stage(0, kstart);
    __syncthreads();
    int cur = 0;
    for (int t = 0; t < nt; ++t) {
        const int k0 = kstart + t * 64;
        if (t + 1 < nt) stage(cur ^ 1, k0 + 64);   // prefetch overlaps compute

        const char* KsC = (const char*)&Ks[cur][0];
        const char* VsC = (const char*)&Vs[cur][0];

        // QK^T swapped: mfma(K, Q) -> D[key][q]; lane holds 16 scores for q=l15.
        f32x4 sc[4];
        __builtin_amdgcn_s_setprio(1);
        #pragma unroll
        for (int kt = 0; kt < 4; ++kt) {
            f32x4 a = { 0.f, 0.f, 0.f, 0.f };
            int r = 16 * kt + l15;
            #pragma unroll
            for (int c = 0; c < 6; ++c) {
                int byteo = (r * 384 + c * 64 + l4 * 16) ^ ((r & 7) << 4);
                bf16x8 kf = *(const bf16x8*)(KsC + byteo);
                a = __builtin_amdgcn_mfma_f32_16x16x32_bf16(kf, qf[c], a, 0, 0, 0);
            }
            sc[kt] = a;
        }
        __builtin_amdgcn_s_setprio(0);

        if (k0 == q0) {   // diagonal tile: causal mask
            int qrow = wave * 16 + l15;
            #pragma unroll
            for (int kt = 0; kt < 4; ++kt)
                #pragma unroll
                for (int r = 0; r < 4; ++r) {
                    int kl = ((kt >> 1) << 5) | (l4 << 3) | ((kt & 1) << 2) | r;
                    if (kl > qrow) sc[kt][r] = -INF;
                }
        }

        // online softmax (row = this lane's q); reduce over l4 groups
        float mx = -INF;
        #pragma unroll
        for (int kt = 0; kt < 4; ++kt)
            #pragma unroll
            for (int r = 0; r < 4; ++r) mx = fmaxf(mx, sc[kt][r]);
        mx = fmaxf(mx, __shfl_xor(mx, 16));
        mx = fmaxf(mx, __shfl_xor(mx, 32));
        float mnew = fmaxf(m_r, mx);
        float corr = __expf(m_r - mnew);
        float rs = 0.f;
        #pragma unroll
        for (int kt = 0; kt < 4; ++kt)
            #pragma unroll
            for (int r = 0; r < 4; ++r) {
                float pv = __expf(sc[kt][r] - mnew);
                sc[kt][r] = pv;
                rs += pv;
            }
        rs += __shfl_xor(rs, 16);
        rs += __shfl_xor(rs, 32);
        l_r = l_r * corr + rs;
        m_r = mnew;

        // rescale oacc rows (q = 4*l4+reg): fetch corr from lane l15=4*l4+reg
        float c_r[4];
        #pragma unroll
        for (int r = 0; r < 4; ++r) c_r[r] = __shfl(corr, 20 * l4 + r);
        #pragma unroll
        for (int dt = 0; dt < 8; ++dt)
            #pragma unroll
            for (int r = 0; r < 4; ++r) oacc[dt][r] *= c_r[r];

        // P -> A-fragments: pure in-lane relabeling (K staging perm)
        bf16x8 pf[2];
        #pragma unroll
        for (int c2 = 0; c2 < 2; ++c2)
            #pragma unroll
            for (int i = 0; i < 8; ++i)
                pf[c2][i] = (bf16)sc[2 * c2 + (i >> 2)][i & 3];

        __builtin_amdgcn_s_setprio(1);
        #pragma unroll
        for (int dt = 0; dt < 8; ++dt) {
            #pragma unroll
            for (int c2 = 0; c2 < 2; ++c2) {
                int d = 16 * dt + l15;
                int byteo = (d * 128 + c2 * 64 + l4 * 16) ^ ((d & 7) << 4);
                bf16x8 vf = *(const bf16x8*)(VsC + byteo);
                oacc[dt] = __builtin_amdgcn_mfma_f32_16x16x32_bf16(pf[c2], vf, oacc[dt], 0, 0, 0);
            }
        }
        __builtin_amdgcn_s_setprio(0);

        __syncthreads();   // drains prefetch vmcnt; all waves done with cur
        cur ^= 1;
    }

    const int slot = (h * 32 + qt) * 4 + chk;
    if (lane < 16) {
        ml[(size_t)slot * 128 + wave * 16 + lane] = m_r;
        ml[(size_t)slot * 128 + 64 + wave * 16 + lane] = l_r;
    }
    bf16* ob = opart + (size_t)slot * 8192;
    #pragma unroll
    for (int dt = 0; dt < 8; ++dt) {
        int d = 16 * dt + l15;
        #pragma unroll
        for (int r = 0; r < 4; ++r) {
            int qr = wave * 16 + 4 * l4 + r;
            ob[qr * 128 + d] = (bf16)oacc[dt][r];
        }
    }
}

// combine up to 4 partials -> ao bf16 [S][H*128]
__global__ __launch_bounds__(256) void z100_attn_combine(
    const bf16* __restrict__ opart, const float* __restrict__ ml, bf16* __restrict__ ao) {
    const int qt = blockIdx.x, h = blockIdx.y;
    const int t = threadIdx.x;
    const int qr = t >> 2, d0 = (t & 3) * 32;
    const int slot0 = (h * 32 + qt) * 4;
    const int np = (qt >> 3) + 1;
    float m[4], l[4], w[4];
    float M = -INF;
    #pragma unroll
    for (int i = 0; i < 4; ++i)
        if (i < np) {
            m[i] = ml[(size_t)(slot0 + i) * 128 + qr];
            l[i] = ml[(size_t)(slot0 + i) * 128 + 64 + qr];
            M = fmaxf(M, m[i]);
        }
    float L = 0.f;
    #pragma unroll
    for (int i = 0; i < 4; ++i)
        if (i < np) {
            w[i] = __expf(m[i] - M);
            L += w[i] * l[i];
        }
    float invL = 1.f / L;
    bf16* orow = ao + (size_t)(qt * 64 + qr) * 2048 + h * 128 + d0;
    for (int d = 0; d < 32; d += 8) {
        float acc[8] = {};
        #pragma unroll
        for (int i = 0; i < 4; ++i)
            if (i < np) {
                bf16x8 a = *(const bf16x8*)(opart + (size_t)(slot0 + i) * 8192 + qr * 128 + d0 + d);
                #pragma unroll
                for (int j = 0; j < 8; ++j) acc[j] += w[i] * (float)a[j];
            }
        bf16x8 o;
        #pragma unroll
        for (int j = 0; j < 8; ++j) o[j] = (bf16)(acc[j] * invL);
        *(bf16x8*)(orow + d) = o;
    }
}

// ---------------------------------------------------------------------------
extern "C" void kernel_launch(void* const* d_in, const int* in_sizes, int n_in,
                              void* d_out, int out_size, void* d_ws, size_t ws_size,
                              hipStream_t stream) {
    (void)in_sizes; (void)n_in; (void)out_size; (void)ws_size;
    const float* x     = (const float*)d_in[0];
    const float* fc    = (const float*)d_in[1];
    const float* fs    = (const float*)d_in[2];
    const float* wq_a  = (const float*)d_in[3];
    const float* q_ln  = (const float*)d_in[4];
    const float* wq_b  = (const float*)d_in[5];
    const float* wkv_a = (const float*)d_in[6];
    const float* kv_ln = (const float*)d_in[7];
    const float* wkv_b = (const float*)d_in[8];
    const float* wo    = (const float*)d_in[9];
    float* out = (float*)d_out;

    char* p = (char*)d_ws;
    auto alloc = [&](size_t bytes) {
        char* r = p;
        p += (bytes + 255) & ~(size_t)255;
        return r;
    };
    // phase-1 buffers (dead before attention) — opart/ml alias this region
    char* phase1  = p;
    bf16* x_bf    = (bf16*)alloc(2048ull * 2048 * 2);
    bf16* wab_bf  = (bf16*)alloc(2176ull * 2048 * 2);  // wq_a(1536)+wkv_a(576)+pad(64)
    float* qa_f   = (float*)alloc(2048ull * 2112 * 4); // [q 1536 | kv_c 512 | k_pe 64]
    bf16* qan_bf  = (bf16*)alloc(2048ull * 1536 * 2);
    // live buffers
    bf16* wqb_bf  = (bf16*)alloc(3072ull * 1536 * 2);
    bf16* wkvb_bf = (bf16*)alloc(4096ull * 512 * 2);
    bf16* wo_bf   = (bf16*)alloc(2048ull * 2048 * 2);
    float* q_f    = (float*)alloc(2048ull * 3072 * 4);
    bf16* kvc_bf  = (bf16*)alloc(2048ull * 512 * 2);
    float* kvb_f  = (float*)alloc(2048ull * 4096 * 4);
    bf16* q_attn  = (bf16*)alloc(16ull * 2048 * 192 * 2);
    bf16* k_attn  = (bf16*)alloc(16ull * 2048 * 192 * 2);
    bf16* v_t     = (bf16*)alloc(16ull * 128 * 2048 * 2);
    bf16* ao_bf   = (bf16*)alloc(2048ull * 2048 * 2);
    // aliased over phase-1 region (x_bf..qan_bf = ~41 MB, need 34.6 MB)
    bf16* opart   = (bf16*)phase1;                     // [2048 slots][64*128]
    float* mlbuf  = (float*)(phase1 + 2048ull * 8192 * 2);

    // casts
    z100_cast<<<4096, 256, 0, stream>>>(x, x_bf, 1048576);
    z100_cast<<<3072, 256, 0, stream>>>(wq_a, wab_bf, 786432);
    z100_cast<<<1152, 256, 0, stream>>>(wkv_a, wab_bf + 1536ull * 2048, 294912);
    z100_zero_bf16<<<512, 256, 0, stream>>>(wab_bf + 2112ull * 2048, 131072);
    z100_cast<<<4608, 256, 0, stream>>>(wq_b, wqb_bf, 1179648);
    z100_cast<<<2048, 256, 0, stream>>>(wkv_b, wkvb_bf, 524288);
    z100_cast<<<4096, 256, 0, stream>>>(wo, wo_bf, 1048576);

    // merged A-GEMM: [q_a | kv_a] in one launch
    z100_gemm_bt<<<dim3(17, 16), 256, 0, stream>>>(x_bf, wab_bf, qa_f, 2048, 2112, 2048, 2112);
    z100_rmsnorm<<<2048, 256, 0, stream>>>(qa_f, 2112, q_ln, qan_bf, 1536, 1.f / 1536.f);
    z100_rmsnorm<<<2048, 256, 0, stream>>>(qa_f + 1536, 2112, kv_ln, kvc_bf, 512, 1.f / 512.f);

    z100_gemm_bt<<<dim3(24, 16), 256, 0, stream>>>(qan_bf, wqb_bf, q_f, 2048, 3072, 1536, 3072);
    z100_gemm_bt<<<dim3(32, 16), 256, 0, stream>>>(kvc_bf, wkvb_bf, kvb_f, 2048, 4096, 512, 4096);

    // attention prep
    z100_q_prep<<<12288, 256, 0, stream>>>(q_f, fc, fs, q_attn);
    z100_k_prep<<<12288, 256, 0, stream>>>(kvb_f, qa_f + 2048, 2112, fc, fs, k_attn);
    z100_v_trans<<<dim3(32, 16), 256, 0, stream>>>(kvb_f, v_t);

    // attention (split-K x4) + combine
    z100_attn<<<dim3(32, 16, 4), 256, 0, stream>>>(q_attn, k_attn, v_t, opart, mlbuf);
    z100_attn_combine<<<dim3(32, 16), 256, 0, stream>>>(opart, mlbuf, ao_bf);

    // output projection (fp32 straight to d_out)
    z100_gemm_bt<<<dim3(16, 16), 256, 0, stream>>>(ao_bf, wo_bf, out, 2048, 2048, 2048, 2048);
}

// Round 4
// 287.063 us; speedup vs baseline: 1.4901x; 1.0111x over previous
//
#include <hip/hip_runtime.h>
#include <cstdint>
#include <cstddef>

typedef __bf16 bf16;
typedef bf16 bf16x8 __attribute__((ext_vector_type(8)));
typedef bf16 bf16x4 __attribute__((ext_vector_type(4)));
typedef float f32x4 __attribute__((ext_vector_type(4)));

typedef __attribute__((address_space(1))) void as1_void;
typedef __attribute__((address_space(3))) void as3_void;

#define INF __builtin_inff()

// ---------------------------------------------------------------------------
// cast fp32 -> bf16, 4 elems/thread
__global__ void z100_cast(const float* __restrict__ s, bf16* __restrict__ d, int n4) {
    int i = blockIdx.x * 256 + threadIdx.x;
    if (i >= n4) return;
    float4 v = ((const float4*)s)[i];
    bf16x4 o = { (bf16)v.x, (bf16)v.y, (bf16)v.z, (bf16)v.w };
    ((bf16x4*)d)[i] = o;
}

__global__ void z100_zero_bf16(bf16* __restrict__ p, int n) {
    int i = blockIdx.x * 256 + threadIdx.x;
    if (i < n) p[i] = (bf16)0.f;
}

// ---------------------------------------------------------------------------
// RMSNorm: one block per row; x fp32 [rows][ldx], out bf16 [rows][N]
__global__ __launch_bounds__(256) void z100_rmsnorm(
    const float* __restrict__ x, int ldx, const float* __restrict__ w,
    bf16* __restrict__ y, int N, float invN) {
    const int row = blockIdx.x;
    const float* xr = x + (size_t)row * ldx;
    float ss = 0.f;
    for (int i = threadIdx.x * 4; i < N; i += 1024) {
        float4 v = *(const float4*)(xr + i);
        ss += v.x * v.x + v.y * v.y + v.z * v.z + v.w * v.w;
    }
    #pragma unroll
    for (int d = 1; d < 64; d <<= 1) ss += __shfl_xor(ss, d);
    __shared__ float red[4];
    if ((threadIdx.x & 63) == 0) red[threadIdx.x >> 6] = ss;
    __syncthreads();
    float tot = red[0] + red[1] + red[2] + red[3];
    float rs = rsqrtf(tot * invN + 1e-6f);
    bf16* yr = y + (size_t)row * N;
    for (int i = threadIdx.x * 4; i < N; i += 1024) {
        float4 v = *(const float4*)(xr + i);
        float4 wv = *(const float4*)(w + i);
        bf16x4 o = { (bf16)(v.x * rs * wv.x), (bf16)(v.y * rs * wv.y),
                     (bf16)(v.z * rs * wv.z), (bf16)(v.w * rs * wv.w) };
        *(bf16x4*)(yr + i) = o;
    }
}

// ---------------------------------------------------------------------------
// GEMM: C[M][N] (fp32, ldc) = A[M][K] (bf16) @ B[N][K]^T (bf16)
// 128x128 tile, BK=32, 256 threads, 2-phase double-buffered async staging.
__global__ __launch_bounds__(256) void z100_gemm_bt(
    const bf16* __restrict__ A, const bf16* __restrict__ B,
    float* __restrict__ C, int M, int N, int K, int ldc) {
    __shared__ alignas(16) bf16 As[2][128 * 32];
    __shared__ alignas(16) bf16 Bs[2][128 * 32];
    const int tid = threadIdx.x;
    const int lane = tid & 63, wave = tid >> 6;
    const int l15 = lane & 15, l4 = lane >> 4;
    const int m0 = blockIdx.y * 128, n0 = blockIdx.x * 128;
    const int wr = (wave >> 1) * 64, wc = (wave & 1) * 64;

    f32x4 acc[4][4] = {};

    const int srow = lane >> 2;        // 0..15
    const int scol = (lane & 3) * 8;   // 0,8,16,24
    const size_t a_base = (size_t)(m0 + wave * 32 + srow) * K + scol;
    const size_t b_base = (size_t)(n0 + wave * 32 + srow) * K + scol;

    auto stage = [&](int buf, int k0) {
        bf16* AsW = &As[buf][0] + wave * 32 * 32;
        bf16* BsW = &Bs[buf][0] + wave * 32 * 32;
        __builtin_amdgcn_global_load_lds((as1_void*)(void*)(A + a_base + k0),
                                         (as3_void*)AsW, 16, 0, 0);
        __builtin_amdgcn_global_load_lds((as1_void*)(void*)(A + a_base + (size_t)16 * K + k0),
                                         (as3_void*)(AsW + 512), 16, 0, 0);
        __builtin_amdgcn_global_load_lds((as1_void*)(void*)(B + b_base + k0),
                                         (as3_void*)BsW, 16, 0, 0);
        __builtin_amdgcn_global_load_lds((as1_void*)(void*)(B + b_base + (size_t)16 * K + k0),
                                         (as3_void*)(BsW + 512), 16, 0, 0);
    };

    stage(0, 0);
    __syncthreads();
    int buf = 0;
    for (int k0 = 0; k0 < K; k0 += 32) {
        if (k0 + 32 < K) stage(buf ^ 1, k0 + 32);   // prefetch overlaps compute
        bf16x8 fa[4], fb[4];
        #pragma unroll
        for (int i = 0; i < 4; ++i)
            fa[i] = *(const bf16x8*)(&As[buf][0] + (wr + 16 * i + l15) * 32 + 8 * l4);
        #pragma unroll
        for (int j = 0; j < 4; ++j)
            fb[j] = *(const bf16x8*)(&Bs[buf][0] + (wc + 16 * j + l15) * 32 + 8 * l4);
        #pragma unroll
        for (int i = 0; i < 4; ++i)
            #pragma unroll
            for (int j = 0; j < 4; ++j)
                acc[i][j] = __builtin_amdgcn_mfma_f32_16x16x32_bf16(fa[i], fb[j], acc[i][j], 0, 0, 0);
        __syncthreads();   // drains prefetch vmcnt + syncs buffer swap
        buf ^= 1;
    }

    #pragma unroll
    for (int i = 0; i < 4; ++i) {
        int row0 = m0 + wr + 16 * i + 4 * l4;
        #pragma unroll
        for (int j = 0; j < 4; ++j) {
            int col = n0 + wc + 16 * j + l15;
            if (col < N) {
                #pragma unroll
                for (int jj = 0; jj < 4; ++jj)
                    C[(size_t)(row0 + jj) * ldc + col] = acc[i][j][jj];
            }
        }
    }
}

// ---------------------------------------------------------------------------
// Q prep: q fp32 [S][3072] -> q_attn bf16 [H][S][192], rope on last 64, *scale
__global__ void z100_q_prep(const float* __restrict__ q,
                            const float* __restrict__ fc, const float* __restrict__ fs,
                            bf16* __restrict__ q_attn) {
    const int TOT = 2048 * 16 * 96;
    int u = blockIdx.x * 256 + threadIdx.x;
    if (u >= TOT) return;
    int e = u % 96;
    int sh = u / 96;
    int h = sh % 16, s = sh / 16;
    const float scale = 0.072168783649f;  // 1/sqrt(192)
    const float* qp = q + (size_t)s * 3072 + h * 192;
    bf16* o = q_attn + ((size_t)h * 2048 + s) * 192;
    if (e < 64) {
        o[2 * e]     = (bf16)(qp[2 * e] * scale);
        o[2 * e + 1] = (bf16)(qp[2 * e + 1] * scale);
    } else {
        int i = e - 64;
        float c = fc[s * 32 + i], sn = fs[s * 32 + i];
        float x1 = qp[128 + 2 * i], x2 = qp[128 + 2 * i + 1];
        o[128 + 2 * i]     = (bf16)((x1 * c - x2 * sn) * scale);
        o[128 + 2 * i + 1] = (bf16)((x1 * sn + x2 * c) * scale);
    }
}

// K prep: kvb fp32 [S][4096] (k_nope), kpe fp32 [S][kpe_ld] -> k_attn [H][S][192]
__global__ void z100_k_prep(const float* __restrict__ kvb, const float* __restrict__ kpe,
                            int kpe_ld,
                            const float* __restrict__ fc, const float* __restrict__ fs,
                            bf16* __restrict__ k_attn) {
    const int TOT = 2048 * 16 * 96;
    int u = blockIdx.x * 256 + threadIdx.x;
    if (u >= TOT) return;
    int e = u % 96;
    int sh = u / 96;
    int h = sh % 16, s = sh / 16;
    bf16* o = k_attn + ((size_t)h * 2048 + s) * 192;
    if (e < 64) {
        const float* kp = kvb + (size_t)s * 4096 + h * 256;
        o[2 * e]     = (bf16)kp[2 * e];
        o[2 * e + 1] = (bf16)kp[2 * e + 1];
    } else {
        int i = e - 64;
        float c = fc[s * 32 + i], sn = fs[s * 32 + i];
        float x1 = kpe[(size_t)s * kpe_ld + 2 * i];
        float x2 = kpe[(size_t)s * kpe_ld + 2 * i + 1];
        o[128 + 2 * i]     = (bf16)(x1 * c - x2 * sn);
        o[128 + 2 * i + 1] = (bf16)(x1 * sn + x2 * c);
    }
}

// V transpose: kvb fp32 [S][4096] (v at h*256+128..) -> vt bf16 [H][128][S]
__global__ __launch_bounds__(256) void z100_v_trans(const float* __restrict__ kvb,
                                                    bf16* __restrict__ vt) {
    const int st = blockIdx.x, h = blockIdx.y;
    const int s0 = st * 64;
    __shared__ alignas(16) bf16 tile[64 * 132];
    const int tid = threadIdx.x;
    #pragma unroll
    for (int i = 0; i < 8; ++i) {
        int slot = i * 256 + tid;
        int r = slot >> 5, c4 = slot & 31;
        float4 v = *(const float4*)(kvb + (size_t)(s0 + r) * 4096 + h * 256 + 128 + c4 * 4);
        bf16x4 o = { (bf16)v.x, (bf16)v.y, (bf16)v.z, (bf16)v.w };
        *(bf16x4*)(tile + r * 132 + c4 * 4) = o;
    }
    __syncthreads();
    #pragma unroll
    for (int i = 0; i < 4; ++i) {
        int slot = i * 256 + tid;
        int d = slot >> 3, ch = slot & 7;
        bf16x8 o;
        #pragma unroll
        for (int j = 0; j < 8; ++j) o[j] = tile[(ch * 8 + j) * 132 + d];
        *(bf16x8*)(vt + ((size_t)h * 128 + d) * 2048 + s0 + ch * 8) = o;
    }
}

// ---------------------------------------------------------------------------
// Flash attention: 8 waves x 128 q-rows, KVBLK=64, double-buffered async LDS,
// split-K(2x1024). grid (16 q-tiles, 16 heads, 2 chunks), 512 threads.
// Swapped QK^T (lane-local score rows), in-lane P->A-frag relabeling.
__global__ __launch_bounds__(512) void z100_attn(
    const bf16* __restrict__ q_attn, const bf16* __restrict__ k_attn,
    const bf16* __restrict__ v_t, bf16* __restrict__ opart, float* __restrict__ ml) {
    const int qt = blockIdx.x, h = blockIdx.y, chk = blockIdx.z;
    const int q0 = qt * 128;
    const int kstart = chk * 1024;
    const int kend = min(q0 + 128, kstart + 1024);
    if (kstart >= kend) return;

    const int tid = threadIdx.x;
    const int lane = tid & 63, wave = tid >> 6;
    const int l15 = lane & 15, l4 = lane >> 4;

    __shared__ alignas(16) bf16 Ks[2][64 * 192];
    __shared__ alignas(16) bf16 Vs[2][128 * 64];

    const bf16* Qh = q_attn + (size_t)h * 2048 * 192;
    const bf16* Kh = k_attn + (size_t)h * 2048 * 192;
    const bf16* Vh = v_t + (size_t)h * 128 * 2048;

    const int wrow_max = q0 + wave * 16 + 15;     // this wave's last q row
    const int diag_k0 = q0 + (wave >> 2) * 64;    // this wave's diagonal k-tile

    bf16x8 qf[6];
    {
        const bf16* qr = Qh + (size_t)(q0 + wave * 16 + l15) * 192 + 8 * l4;
        #pragma unroll
        for (int c = 0; c < 6; ++c) qf[c] = *(const bf16x8*)(qr + 32 * c);
    }

    // Per-lane staging source offsets: LDS dest LINEAR, K-row permutation +
    // XOR bank swizzle applied to the GLOBAL source (m173 pattern).
    // 8 waves: 3 K-slices + 2 V-slices of 1KB each per wave.
    int koff[3], voff[2];
    #pragma unroll
    for (int i = 0; i < 3; ++i) {
        int off = (wave * 3 + i) * 1024 + lane * 16;   // byte offset in K tile
        int r = off / 384;
        int ch = (off % 384) >> 4;
        int ksrc = (r & 0x23) | ((r & 0x0C) << 1) | ((r & 0x10) >> 2);
        koff[i] = ksrc * 192 + (ch ^ (r & 7)) * 8;
    }
    #pragma unroll
    for (int i = 0; i < 2; ++i) {
        int off = (wave * 2 + i) * 1024 + lane * 16;   // byte offset in V tile
        int d = off >> 7;
        int ch = (off >> 4) & 7;
        voff[i] = d * 2048 + (ch ^ (d & 7)) * 8;
    }

    auto stage = [&](int buf, int k0) {
        #pragma unroll
        for (int i = 0; i < 3; ++i)
            __builtin_amdgcn_global_load_lds(
                (as1_void*)(void*)(Kh + (size_t)k0 * 192 + koff[i]),
                (as3_void*)((char*)&Ks[buf][0] + (wave * 3 + i) * 1024), 16, 0, 0);
        #pragma unroll
        for (int i = 0; i < 2; ++i)
            __builtin_amdgcn_global_load_lds(
                (as1_void*)(void*)(Vh + k0 + voff[i]),
                (as3_void*)((char*)&Vs[buf][0] + (wave * 2 + i) * 1024), 16, 0, 0);
    };

    f32x4 oacc[8] = {};
    float m_r = -INF, l_r = 0.f;
    const int nt = (kend - kstart) >> 6;

    stage(0, kstart);
    __syncthreads();
    int cur = 0;
    for (int t = 0; t < nt; ++t) {
        const int k0 = kstart + t * 64;
        if (t + 1 < nt) stage(cur ^ 1, k0 + 64);   // prefetch overlaps compute

        if (k0 <= wrow_max) {   // waves 0-3 skip the block's last k-tile
            const char* KsC = (const char*)&Ks[cur][0];
            const char* VsC = (const char*)&Vs[cur][0];

            // QK^T swapped: mfma(K, Q) -> D[key][q]; lane holds 16 scores, q=l15.
            f32x4 sc[4];
            __builtin_amdgcn_s_setprio(1);
            #pragma unroll
            for (int kt = 0; kt < 4; ++kt) {
                f32x4 a = { 0.f, 0.f, 0.f, 0.f };
                int r = 16 * kt + l15;
                #pragma unroll
                for (int c = 0; c < 6; ++c) {
                    int byteo = (r * 384 + c * 64 + l4 * 16) ^ ((r & 7) << 4);
                    bf16x8 kf = *(const bf16x8*)(KsC + byteo);
                    a = __builtin_amdgcn_mfma_f32_16x16x32_bf16(kf, qf[c], a, 0, 0, 0);
                }
                sc[kt] = a;
            }
            __builtin_amdgcn_s_setprio(0);

            if (k0 == diag_k0) {   // causal mask at this wave's diagonal tile
                int qrow = (wave & 3) * 16 + l15;   // row - k0
                #pragma unroll
                for (int kt = 0; kt < 4; ++kt)
                    #pragma unroll
                    for (int r = 0; r < 4; ++r) {
                        int kl = ((kt >> 1) << 5) | (l4 << 3) | ((kt & 1) << 2) | r;
                        if (kl > qrow) sc[kt][r] = -INF;
                    }
            }

            // online softmax (row = this lane's q); reduce over l4 groups
            float mx = -INF;
            #pragma unroll
            for (int kt = 0; kt < 4; ++kt)
                #pragma unroll
                for (int r = 0; r < 4; ++r) mx = fmaxf(mx, sc[kt][r]);
            mx = fmaxf(mx, __shfl_xor(mx, 16));
            mx = fmaxf(mx, __shfl_xor(mx, 32));
            float mnew = fmaxf(m_r, mx);
            float corr = __expf(m_r - mnew);
            float rs = 0.f;
            #pragma unroll
            for (int kt = 0; kt < 4; ++kt)
                #pragma unroll
                for (int r = 0; r < 4; ++r) {
                    float pv = __expf(sc[kt][r] - mnew);
                    sc[kt][r] = pv;
                    rs += pv;
                }
            rs += __shfl_xor(rs, 16);
            rs += __shfl_xor(rs, 32);
            l_r = l_r * corr + rs;
            m_r = mnew;

            // rescale oacc rows (q = 4*l4+reg): corr lives in lane l15=4*l4+reg
            float c_r[4];
            #pragma unroll
            for (int r = 0; r < 4; ++r) c_r[r] = __shfl(corr, 20 * l4 + r);
            #pragma unroll
            for (int dt = 0; dt < 8; ++dt)
                #pragma unroll
                for (int r = 0; r < 4; ++r) oacc[dt][r] *= c_r[r];

            // P -> A-fragments: pure in-lane relabeling (K staging perm)
            bf16x8 pf[2];
            #pragma unroll
            for (int c2 = 0; c2 < 2; ++c2)
                #pragma unroll
                for (int i = 0; i < 8; ++i)
                    pf[c2][i] = (bf16)sc[2 * c2 + (i >> 2)][i & 3];

            __builtin_amdgcn_s_setprio(1);
            #pragma unroll
            for (int dt = 0; dt < 8; ++dt) {
                #pragma unroll
                for (int c2 = 0; c2 < 2; ++c2) {
                    int d = 16 * dt + l15;
                    int byteo = (d * 128 + c2 * 64 + l4 * 16) ^ ((d & 7) << 4);
                    bf16x8 vf = *(const bf16x8*)(VsC + byteo);
                    oacc[dt] = __builtin_amdgcn_mfma_f32_16x16x32_bf16(pf[c2], vf, oacc[dt], 0, 0, 0);
                }
            }
            __builtin_amdgcn_s_setprio(0);
        }

        __syncthreads();   // drains prefetch vmcnt; all waves done with cur
        cur ^= 1;
    }

    // write partial: slot = (h*16+qt)*2 + chk; 128 rows x 128 cols
    const int slot = (h * 16 + qt) * 2 + chk;
    const int qr_base = wave * 16;
    if (lane < 16) {
        ml[(size_t)slot * 256 + qr_base + lane] = m_r;
        ml[(size_t)slot * 256 + 128 + qr_base + lane] = l_r;
    }
    bf16* ob = opart + (size_t)slot * 16384;
    #pragma unroll
    for (int dt = 0; dt < 8; ++dt) {
        int d = 16 * dt + l15;
        #pragma unroll
        for (int r = 0; r < 4; ++r) {
            int qr = qr_base + 4 * l4 + r;
            ob[qr * 128 + d] = (bf16)oacc[dt][r];
        }
    }
}

// combine up to 2 partials -> ao bf16 [S][H*128]; 128 q-rows per block
__global__ __launch_bounds__(256) void z100_attn_combine(
    const bf16* __restrict__ opart, const float* __restrict__ ml, bf16* __restrict__ ao) {
    const int qt = blockIdx.x, h = blockIdx.y;
    const int t = threadIdx.x;
    const int qr = t >> 1, d0 = (t & 1) * 64;
    const int slot0 = (h * 16 + qt) * 2;
    const int np = (qt >= 8) ? 2 : 1;
    float m[2], l[2], w[2];
    float M = -INF;
    #pragma unroll
    for (int i = 0; i < 2; ++i)
        if (i < np) {
            m[i] = ml[(size_t)(slot0 + i) * 256 + qr];
            l[i] = ml[(size_t)(slot0 + i) * 256 + 128 + qr];
            M = fmaxf(M, m[i]);
        }
    float L = 0.f;
    #pragma unroll
    for (int i = 0; i < 2; ++i)
        if (i < np) {
            w[i] = __expf(m[i] - M);
            L += w[i] * l[i];
        }
    float invL = 1.f / L;
    bf16* orow = ao + (size_t)(qt * 128 + qr) * 2048 + h * 128 + d0;
    for (int d = 0; d < 64; d += 8) {
        float acc[8] = {};
        #pragma unroll
        for (int i = 0; i < 2; ++i)
            if (i < np) {
                bf16x8 a = *(const bf16x8*)(opart + (size_t)(slot0 + i) * 16384 + qr * 128 + d0 + d);
                #pragma unroll
                for (int j = 0; j < 8; ++j) acc[j] += w[i] * (float)a[j];
            }
        bf16x8 o;
        #pragma unroll
        for (int j = 0; j < 8; ++j) o[j] = (bf16)(acc[j] * invL);
        *(bf16x8*)(orow + d) = o;
    }
}

// ---------------------------------------------------------------------------
extern "C" void kernel_launch(void* const* d_in, const int* in_sizes, int n_in,
                              void* d_out, int out_size, void* d_ws, size_t ws_size,
                              hipStream_t stream) {
    (void)in_sizes; (void)n_in; (void)out_size; (void)ws_size;
    const float* x     = (const float*)d_in[0];
    const float* fc    = (const float*)d_in[1];
    const float* fs    = (const float*)d_in[2];
    const float* wq_a  = (const float*)d_in[3];
    const float* q_ln  = (const float*)d_in[4];
    const float* wq_b  = (const float*)d_in[5];
    const float* wkv_a = (const float*)d_in[6];
    const float* kv_ln = (const float*)d_in[7];
    const float* wkv_b = (const float*)d_in[8];
    const float* wo    = (const float*)d_in[9];
    float* out = (float*)d_out;

    char* p = (char*)d_ws;
    auto alloc = [&](size_t bytes) {
        char* r = p;
        p += (bytes + 255) & ~(size_t)255;
        return r;
    };
    // phase-1 buffers (dead before attention) — opart/ml alias this region
    char* phase1  = p;
    bf16* x_bf    = (bf16*)alloc(2048ull * 2048 * 2);
    bf16* wab_bf  = (bf16*)alloc(2176ull * 2048 * 2);  // wq_a(1536)+wkv_a(576)+pad(64)
    float* qa_f   = (float*)alloc(2048ull * 2112 * 4); // [q 1536 | kv_c 512 | k_pe 64]
    bf16* qan_bf  = (bf16*)alloc(2048ull * 1536 * 2);
    // live buffers
    bf16* wqb_bf  = (bf16*)alloc(3072ull * 1536 * 2);
    bf16* wkvb_bf = (bf16*)alloc(4096ull * 512 * 2);
    bf16* wo_bf   = (bf16*)alloc(2048ull * 2048 * 2);
    float* q_f    = (float*)alloc(2048ull * 3072 * 4);
    bf16* kvc_bf  = (bf16*)alloc(2048ull * 512 * 2);
    float* kvb_f  = (float*)alloc(2048ull * 4096 * 4);
    bf16* q_attn  = (bf16*)alloc(16ull * 2048 * 192 * 2);
    bf16* k_attn  = (bf16*)alloc(16ull * 2048 * 192 * 2);
    bf16* v_t     = (bf16*)alloc(16ull * 128 * 2048 * 2);
    bf16* ao_bf   = (bf16*)alloc(2048ull * 2048 * 2);
    // aliased over phase-1 region (x_bf..qan_bf ≈ 41 MB, need 16.5 MB)
    bf16* opart   = (bf16*)phase1;                     // [512 slots][128*128]
    float* mlbuf  = (float*)(phase1 + 512ull * 16384 * 2);

    // casts
    z100_cast<<<4096, 256, 0, stream>>>(x, x_bf, 1048576);
    z100_cast<<<3072, 256, 0, stream>>>(wq_a, wab_bf, 786432);
    z100_cast<<<1152, 256, 0, stream>>>(wkv_a, wab_bf + 1536ull * 2048, 294912);
    z100_zero_bf16<<<512, 256, 0, stream>>>(wab_bf + 2112ull * 2048, 131072);
    z100_cast<<<4608, 256, 0, stream>>>(wq_b, wqb_bf, 1179648);
    z100_cast<<<2048, 256, 0, stream>>>(wkv_b, wkvb_bf, 524288);
    z100_cast<<<4096, 256, 0, stream>>>(wo, wo_bf, 1048576);

    // merged A-GEMM: [q_a | kv_a] in one launch
    z100_gemm_bt<<<dim3(17, 16), 256, 0, stream>>>(x_bf, wab_bf, qa_f, 2048, 2112, 2048, 2112);
    z100_rmsnorm<<<2048, 256, 0, stream>>>(qa_f, 2112, q_ln, qan_bf, 1536, 1.f / 1536.f);
    z100_rmsnorm<<<2048, 256, 0, stream>>>(qa_f + 1536, 2112, kv_ln, kvc_bf, 512, 1.f / 512.f);

    z100_gemm_bt<<<dim3(24, 16), 256, 0, stream>>>(qan_bf, wqb_bf, q_f, 2048, 3072, 1536, 3072);
    z100_gemm_bt<<<dim3(32, 16), 256, 0, stream>>>(kvc_bf, wkvb_bf, kvb_f, 2048, 4096, 512, 4096);

    // attention prep
    z100_q_prep<<<12288, 256, 0, stream>>>(q_f, fc, fs, q_attn);
    z100_k_prep<<<12288, 256, 0, stream>>>(kvb_f, qa_f + 2048, 2112, fc, fs, k_attn);
    z100_v_trans<<<dim3(32, 16), 256, 0, stream>>>(kvb_f, v_t);

    // attention (8-wave 128-row blocks, split-K x2) + combine
    z100_attn<<<dim3(16, 16, 2), 512, 0, stream>>>(q_attn, k_attn, v_t, opart, mlbuf);
    z100_attn_combine<<<dim3(16, 16), 256, 0, stream>>>(opart, mlbuf, ao_bf);

    // output projection (fp32 straight to d_out)
    z100_gemm_bt<<<dim3(16, 16), 256, 0, stream>>>(ao_bf, wo_bf, out, 2048, 2048, 2048, 2048);
}